// Round 1
// baseline (262.563 us; speedup 1.0000x reference)
//
#include <hip/hip_runtime.h>
#include <math.h>

#define Bsz 64
#define Himg 224
#define HS (Himg*Himg)        // 50176
#define PW 111
#define PP (PW*PW)            // 12321
#define Fn 8
#define FEAT (Fn*PP)          // 98568
#define N1 512
#define N2 256
#define N3 1000
#define KC 32
#define CHUNK 384
#define NCH 257               // ceil(FEAT/CHUNK)

// ---------------- channel sum: s[b,y,x] = sum_c x[b,c,y,x] ----------------
__global__ void k_chsum(const float* __restrict__ x, float* __restrict__ s) {
  int i = blockIdx.x * 256 + threadIdx.x;
  if (i >= Bsz * HS) return;
  int b = i / HS, p = i - b * HS;
  const float* xb = x + (size_t)b * 3 * HS + p;
  s[i] = xb[0] + xb[HS] + xb[2 * HS];
}

// ------------- conv3x3 (8 filt) + relu + maxpool2x2 -> flat ----------------
__global__ void k_convpool(const float* __restrict__ s, const float* __restrict__ filt,
                           float* __restrict__ flat) {
  int i = blockIdx.x * 256 + threadIdx.x;
  if (i >= Bsz * PP) return;
  int b = i / PP, r = i - b * PP;
  int py = r / PW, px = r - py * PW;
  const float* sp = s + (size_t)b * HS + (size_t)(2 * py) * Himg + 2 * px;
  float p[4][4];
#pragma unroll
  for (int dy = 0; dy < 4; dy++)
#pragma unroll
    for (int dx = 0; dx < 4; dx++)
      p[dy][dx] = sp[dy * Himg + dx];
  float* outb = flat + (size_t)b * FEAT + r;
#pragma unroll
  for (int f = 0; f < Fn; f++) {
    float mx = 0.f;  // relu floor: max(0, conv...) == max over relu'd convs
#pragma unroll
    for (int oy = 0; oy < 2; oy++)
#pragma unroll
      for (int ox = 0; ox < 2; ox++) {
        float c = 0.f;
#pragma unroll
        for (int dy = 0; dy < 3; dy++)
#pragma unroll
          for (int dx = 0; dx < 3; dx++)
            c = fmaf(p[oy + dy][ox + dx], filt[f * 9 + dy * 3 + dx], c);
        mx = fmaxf(mx, c);
      }
    outb[(size_t)f * PP] = mx;
  }
}

// ---------------- GEMM1 split-K partials: (64 x K) @ (K x 512) -------------
// grid (2 n-tiles, NCH k-chunks), block 256.
// Wave w handles m-rows [w*16, w*16+16); thread lane handles 4 columns.
__global__ void __launch_bounds__(256) k_gemm1(const float* __restrict__ A,
                                               const float* __restrict__ W,
                                               float* __restrict__ partial) {
  __shared__ float lds[KC][64];  // A^T tile: [k][m]
  const int t = threadIdx.x;
  const int nt = blockIdx.x;
  const int c = blockIdx.y;
  const int k0 = c * CHUNK;
  const int kend = min(k0 + CHUNK, FEAT);
  const int lane = t & 63;
  const int mg16 = (t >> 6) * 16;
  const int ncol = nt * 256 + lane * 4;
  const int m_s = t >> 2;
  const int kq = (t & 3) * 8;
  float4 acc[16];
#pragma unroll
  for (int i = 0; i < 16; i++) acc[i] = make_float4(0.f, 0.f, 0.f, 0.f);

  for (int kt = k0; kt < kend; kt += KC) {
    __syncthreads();
#pragma unroll
    for (int j = 0; j < 8; j++) {
      int kk = kq + j;
      int kg = kt + kk;
      lds[kk][m_s] = (kg < kend) ? A[(size_t)m_s * FEAT + kg] : 0.f;
    }
    __syncthreads();
    const int klim = kend - kt;
    if (klim >= KC) {
      const float* wr = W + (size_t)kt * N1 + ncol;
#pragma unroll
      for (int kk = 0; kk < KC; kk++) {
        float4 w = *(const float4*)wr;
        wr += N1;
        const float* ar = &lds[kk][mg16];
#pragma unroll
        for (int i = 0; i < 16; i++) {
          float a_ = ar[i];
          acc[i].x = fmaf(a_, w.x, acc[i].x);
          acc[i].y = fmaf(a_, w.y, acc[i].y);
          acc[i].z = fmaf(a_, w.z, acc[i].z);
          acc[i].w = fmaf(a_, w.w, acc[i].w);
        }
      }
    } else {
      const float* wr = W + (size_t)kt * N1 + ncol;
      for (int kk = 0; kk < klim; kk++) {
        float4 w = *(const float4*)wr;
        wr += N1;
        const float* ar = &lds[kk][mg16];
#pragma unroll
        for (int i = 0; i < 16; i++) {
          float a_ = ar[i];
          acc[i].x = fmaf(a_, w.x, acc[i].x);
          acc[i].y = fmaf(a_, w.y, acc[i].y);
          acc[i].z = fmaf(a_, w.z, acc[i].z);
          acc[i].w = fmaf(a_, w.w, acc[i].w);
        }
      }
    }
  }
  float* pp = partial + ((size_t)c * Bsz + mg16) * N1 + ncol;
#pragma unroll
  for (int i = 0; i < 16; i++)
    *(float4*)(pp + (size_t)i * N1) = acc[i];
}

// -------------- reduce partials + bias + relu -> h1 [64,512] ---------------
__global__ void k_red1(const float* __restrict__ partial, const float* __restrict__ b1,
                       float* __restrict__ h1) {
  int i = blockIdx.x * 256 + threadIdx.x;
  if (i >= Bsz * N1) return;
  float sum = 0.f;
  for (int c = 0; c < NCH; c++) sum += partial[(size_t)c * Bsz * N1 + i];
  int n = i & (N1 - 1);
  h1[i] = fmaxf(sum + b1[n], 0.f);
}

// -------------- GEMM2: h2 = relu(h1 @ W2 + b2), [64,256] -------------------
__global__ void __launch_bounds__(256) k_gemm2(const float* __restrict__ h1,
                                               const float* __restrict__ W2,
                                               const float* __restrict__ b2,
                                               float* __restrict__ h2) {
  const int m = blockIdx.x;
  const int t = threadIdx.x;
  __shared__ float a[N1];
  a[t] = h1[(size_t)m * N1 + t];
  a[256 + t] = h1[(size_t)m * N1 + 256 + t];
  __syncthreads();
  float sum = b2[t];
#pragma unroll 8
  for (int k = 0; k < N1; k++) sum = fmaf(a[k], W2[(size_t)k * N2 + t], sum);
  h2[(size_t)m * N2 + t] = fmaxf(sum, 0.f);
}

// -------------- GEMM3 + softmax: out = softmax(h2 @ Wo + bo) ---------------
__global__ void __launch_bounds__(256) k_out(const float* __restrict__ h2,
                                             const float* __restrict__ Wo,
                                             const float* __restrict__ bo,
                                             float* __restrict__ out) {
  const int m = blockIdx.x;
  const int t = threadIdx.x;
  __shared__ float a[N2];
  __shared__ float red[8];
  a[t] = h2[(size_t)m * N2 + t];
  __syncthreads();
  float vals[4];
  float vmax = -3.4e38f;
#pragma unroll
  for (int j = 0; j < 4; j++) {
    int n = j * 256 + t;
    float sum = -3.4e38f;
    if (n < N3) {
      sum = bo[n];
#pragma unroll 8
      for (int k = 0; k < N2; k++) sum = fmaf(a[k], Wo[(size_t)k * N3 + n], sum);
    }
    vals[j] = sum;
    vmax = fmaxf(vmax, sum);
  }
#pragma unroll
  for (int off = 32; off > 0; off >>= 1) vmax = fmaxf(vmax, __shfl_xor(vmax, off));
  const int wid = t >> 6;
  if ((t & 63) == 0) red[wid] = vmax;
  __syncthreads();
  vmax = fmaxf(fmaxf(red[0], red[1]), fmaxf(red[2], red[3]));
  float ev[4];
  float esum = 0.f;
#pragma unroll
  for (int j = 0; j < 4; j++) {
    int n = j * 256 + t;
    float e = (n < N3) ? __expf(vals[j] - vmax) : 0.f;
    ev[j] = e;
    esum += e;
  }
#pragma unroll
  for (int off = 32; off > 0; off >>= 1) esum += __shfl_xor(esum, off);
  if ((t & 63) == 0) red[4 + wid] = esum;
  __syncthreads();
  esum = red[4] + red[5] + red[6] + red[7];
  float inv = 1.f / esum;
#pragma unroll
  for (int j = 0; j < 4; j++) {
    int n = j * 256 + t;
    if (n < N3) out[(size_t)m * N3 + n] = ev[j] * inv;
  }
}

extern "C" void kernel_launch(void* const* d_in, const int* in_sizes, int n_in,
                              void* d_out, int out_size, void* d_ws, size_t ws_size,
                              hipStream_t stream) {
  const float* x = (const float*)d_in[0];
  const float* filters = (const float*)d_in[1];
  const float* W1 = (const float*)d_in[2];
  const float* b1 = (const float*)d_in[3];
  const float* W2 = (const float*)d_in[4];
  const float* b2 = (const float*)d_in[5];
  const float* Wo = (const float*)d_in[6];
  const float* bo = (const float*)d_in[7];
  float* out = (float*)d_out;

  float* ws = (float*)d_ws;
  float* s = ws;                                    // 64*224*224
  float* flat = s + (size_t)Bsz * HS;               // 64*98568
  float* partial = flat + (size_t)Bsz * FEAT;       // NCH*64*512
  float* h1 = partial + (size_t)NCH * Bsz * N1;     // 64*512
  float* h2 = h1 + (size_t)Bsz * N1;                // 64*256

  k_chsum<<<(Bsz * HS + 255) / 256, 256, 0, stream>>>(x, s);
  k_convpool<<<(Bsz * PP + 255) / 256, 256, 0, stream>>>(s, filters, flat);
  dim3 g1(2, NCH);
  k_gemm1<<<g1, 256, 0, stream>>>(flat, W1, partial);
  k_red1<<<(Bsz * N1 + 255) / 256, 256, 0, stream>>>(partial, b1, h1);
  k_gemm2<<<Bsz, 256, 0, stream>>>(h1, W2, b2, h2);
  k_out<<<Bsz, 256, 0, stream>>>(h2, Wo, bo, out);
}